// Round 5
// baseline (1113.452 us; speedup 1.0000x reference)
//
#include <hip/hip_runtime.h>

#define L_  6
#define E_  384
#define T_  256
#define H_  6
#define D_  64
#define V_  65
#define FF_ 1536
#define B_  64
#define BT_ (B_*T_)    // 16384 rows
#define HD_ 384

typedef __attribute__((ext_vector_type(8))) short short8;
typedef __attribute__((ext_vector_type(4))) float f32x4;
typedef unsigned short us;
typedef unsigned int u32;

__device__ __forceinline__ us f2bf(float f) {
  u32 u = __float_as_uint(f);
  u32 r = (u + 0x7fffu + ((u >> 16) & 1u)) >> 16;  // RNE
  return (us)r;
}
__device__ __forceinline__ float bf2f(us v) {
  return __uint_as_float(((u32)v) << 16);
}

// XCD-chunked bijective block remap (requires gridDim.x % 8 == 0).
__device__ __forceinline__ int xcd_swz(int b, int nwg) {
  const int q = nwg >> 3;
  return (b & 7) * q + (b >> 3);
}

// ---------------------------------------------------------------------------
// Embedding: h[b,t,:] = tok_emb[x[b,t]] + pos_emb[t]  -> bf16
// ---------------------------------------------------------------------------
__global__ void embed_kernel(const int* __restrict__ x, const float* __restrict__ tok,
                             const float* __restrict__ pos, us* __restrict__ h) {
  const int total8 = BT_ * E_ / 8;
  for (int i = blockIdx.x * blockDim.x + threadIdx.x; i < total8;
       i += gridDim.x * blockDim.x) {
    const int flat = i << 3;
    const int row  = flat / E_;
    const int e    = flat - row * E_;
    const int id   = x[row];
    const float4 a0 = *reinterpret_cast<const float4*>(tok + id * E_ + e);
    const float4 a1 = *reinterpret_cast<const float4*>(tok + id * E_ + e + 4);
    const float4 p0 = *reinterpret_cast<const float4*>(pos + (row & (T_ - 1)) * E_ + e);
    const float4 p1 = *reinterpret_cast<const float4*>(pos + (row & (T_ - 1)) * E_ + e + 4);
    short8 o;
    o[0] = (short)f2bf(a0.x + p0.x); o[1] = (short)f2bf(a0.y + p0.y);
    o[2] = (short)f2bf(a0.z + p0.z); o[3] = (short)f2bf(a0.w + p0.w);
    o[4] = (short)f2bf(a1.x + p1.x); o[5] = (short)f2bf(a1.y + p1.y);
    o[6] = (short)f2bf(a1.z + p1.z); o[7] = (short)f2bf(a1.w + p1.w);
    *reinterpret_cast<short8*>(h + flat) = o;
  }
}

// ---------------------------------------------------------------------------
// LayerNorm: bf16 in, bf16 out. One wave per row; lanes 0-47 hold 8 cols each.
// ---------------------------------------------------------------------------
template<int DDOF>
__global__ void ln_kernel(const us* __restrict__ in, us* __restrict__ out,
                          const float* __restrict__ g, const float* __restrict__ b) {
  const int wave = threadIdx.x >> 6;
  const int lane = threadIdx.x & 63;
  const int row  = (blockIdx.x << 2) + wave;
  const bool act = lane < 48;
  float xv[8];
  float sum = 0.f, sq = 0.f;
  if (act) {
    const short8 v = *reinterpret_cast<const short8*>(in + (size_t)row * E_ + lane * 8);
#pragma unroll
    for (int j = 0; j < 8; ++j) {
      xv[j] = bf2f((us)v[j]);
      sum += xv[j];
      sq  += xv[j] * xv[j];
    }
  }
#pragma unroll
  for (int off = 32; off > 0; off >>= 1) {
    sum += __shfl_xor(sum, off);
    sq  += __shfl_xor(sq, off);
  }
  const float mean = sum * (1.f / E_);
  const float var  = (sq - E_ * mean * mean) * (1.f / (E_ - DDOF));
  const float inv  = rsqrtf(var + 1e-5f);
  if (act) {
    const int c0 = lane * 8;
    const float4 g0 = *reinterpret_cast<const float4*>(g + c0);
    const float4 g1 = *reinterpret_cast<const float4*>(g + c0 + 4);
    const float4 b0 = *reinterpret_cast<const float4*>(b + c0);
    const float4 b1 = *reinterpret_cast<const float4*>(b + c0 + 4);
    const float gv[8] = {g0.x, g0.y, g0.z, g0.w, g1.x, g1.y, g1.z, g1.w};
    const float bv[8] = {b0.x, b0.y, b0.z, b0.w, b1.x, b1.y, b1.z, b1.w};
    short8 o;
#pragma unroll
    for (int j = 0; j < 8; ++j)
      o[j] = (short)f2bf(gv[j] * (xv[j] - mean) * inv + bv[j]);
    *reinterpret_cast<short8*>(out + (size_t)row * E_ + c0) = o;
  }
}

// ---------------------------------------------------------------------------
// Weight transpose + fp32->bf16: dst[n][k] = src[k][n], zero-pad n in [N,Ndst)
// ---------------------------------------------------------------------------
__global__ void transpose_w(const float* __restrict__ src, us* __restrict__ dst,
                            int K, int N, int Ndst, long srcLS, long dstLS) {
  __shared__ float t[32][33];
  const int n0 = blockIdx.x << 5, k0 = blockIdx.y << 5;
  const int tx = threadIdx.x & 31, ty = threadIdx.x >> 5;
  const float* s = src + (size_t)blockIdx.z * srcLS;
  us* d = dst + (size_t)blockIdx.z * dstLS;
#pragma unroll
  for (int j = 0; j < 32; j += 8) {
    const int n = n0 + tx;
    t[ty + j][tx] = (n < N) ? s[(size_t)(k0 + ty + j) * N + n] : 0.f;
  }
  __syncthreads();
#pragma unroll
  for (int j = 0; j < 32; j += 8) {
    const int n = n0 + ty + j;
    if (n < Ndst) d[(size_t)n * K + k0 + tx] = f2bf(t[tx][ty + j]);
  }
}

// ---------------------------------------------------------------------------
// Async global->LDS staging of a ROWS x (CHPR*8 us) bf16 tile. LDS dest is
// linear; XOR chunk swizzle applied on the GLOBAL source side (rule #21).
// ---------------------------------------------------------------------------
template<int ROWS, int CHPR, int NTH>
__device__ __forceinline__ void stageG(const us* g, int rowUs, us* lds, int tid) {
#pragma unroll
  for (int j = 0; j < ROWS * CHPR / NTH; ++j) {
    const int fl  = j * NTH + tid;
    const int row = fl / CHPR;
    const int c   = fl % CHPR;
    const int gc  = (CHPR == 8) ? (c ^ (row & 7)) : (c ^ ((row >> 1) & 3));
    const us* src = g + (size_t)row * rowUs + gc * 8;
    __builtin_amdgcn_global_load_lds(
        (const __attribute__((address_space(1))) u32*)src,
        (__attribute__((address_space(3))) u32*)(lds + ((fl >> 6) << 9)),
        16, 0, 0);
  }
}

// ---------------------------------------------------------------------------
// MFMA GEMM: C = A[M,K] @ Bt[N,K]^T. Tile (WVM*FM*16)x(WVN*FN*16), BK=32,
// WVM x WVN waves, per-wave FMxFN frags of 16x16x32_bf16. 3-buffer pipeline,
// counted vmcnt (never drains mid-loop), raw s_barrier, 1 barrier/step.
// EPI: 0 = QKV split (q/k -> O0 [BT][768] bf16, v -> O1 [B*H][64][256] bf16)
//      1 = +bias +Res(bf16) -> bf16 O0
//      2 = +bias +ReLU -> bf16 O0
//      3 = +bias, col<65 -> fp32 O0 stride 65 (LM head)
// ---------------------------------------------------------------------------
template<int WVM, int WVN, int FM, int FN, int EPI>
__global__ __launch_bounds__(WVM * WVN * 64)
void gemm_mfma(const us* __restrict__ A, const us* __restrict__ Bt,
               const float* __restrict__ bias, const us* Res,
               void* O0, void* O1, int N, int K, int gx) {
  constexpr int NTH = WVM * WVN * 64;
  constexpr int BM = WVM * FM * 16, BN = WVN * FN * 16;
  constexpr int LPS = (BM + BN) * 4 / NTH;   // loads/thread/stage
  __shared__ us As[3][BM * 32];
  __shared__ us Bs[3][BN * 32];
  const int tid = threadIdx.x;
  const int lid = xcd_swz(blockIdx.x, gridDim.x);
  const int bnI = lid % gx, bmI = lid / gx;
  const int bm = bmI * BM, bn = bnI * BN;
  const int wv = tid >> 6, ln = tid & 63;
  const int fm = ln & 15, fg = ln >> 4;
  const int wm = (wv / WVN) * (FM * 16), wn = (wv % WVN) * (FN * 16);
  const us* Abase = A + (size_t)bm * K;
  const us* Bbase = Bt + (size_t)bn * K;

  f32x4 acc[FM][FN];
  const f32x4 zz = {0.f, 0.f, 0.f, 0.f};
#pragma unroll
  for (int i = 0; i < FM; ++i)
#pragma unroll
    for (int j = 0; j < FN; ++j) acc[i][j] = zz;

  const int NT = K >> 5;
  stageG<BM, 4, NTH>(Abase,      K, As[0], tid);
  stageG<BN, 4, NTH>(Bbase,      K, Bs[0], tid);
  stageG<BM, 4, NTH>(Abase + 32, K, As[1], tid);
  stageG<BN, 4, NTH>(Bbase + 32, K, Bs[1], tid);

  int cur = 0;
  for (int t = 0; t < NT; ++t) {
    if (t + 1 < NT) {
      asm volatile("s_waitcnt vmcnt(%0)" :: "n"(LPS) : "memory");
    } else {
      asm volatile("s_waitcnt vmcnt(0)" ::: "memory");
    }
    __builtin_amdgcn_s_barrier();
    __builtin_amdgcn_sched_barrier(0);
    if (t + 2 < NT) {
      const int nxt = (cur + 2 >= 3) ? cur - 1 : cur + 2;
      stageG<BM, 4, NTH>(Abase + (t + 2) * 32, K, As[nxt], tid);
      stageG<BN, 4, NTH>(Bbase + (t + 2) * 32, K, Bs[nxt], tid);
    }
    short8 af[FM], bfr[FN];
#pragma unroll
    for (int mt = 0; mt < FM; ++mt) {
      const int row = wm + mt * 16 + fm;
      af[mt] = *(const short8*)(As[cur] + row * 32 + ((fg ^ ((row >> 1) & 3)) << 3));
    }
#pragma unroll
    for (int nt = 0; nt < FN; ++nt) {
      const int row = wn + nt * 16 + fm;
      bfr[nt] = *(const short8*)(Bs[cur] + row * 32 + ((fg ^ ((row >> 1) & 3)) << 3));
    }
#pragma unroll
    for (int mt = 0; mt < FM; ++mt)
#pragma unroll
      for (int nt = 0; nt < FN; ++nt)
        acc[mt][nt] = __builtin_amdgcn_mfma_f32_16x16x32_bf16(af[mt], bfr[nt], acc[mt][nt], 0, 0, 0);
    cur = (cur + 1 == 3) ? 0 : cur + 1;
  }

  // ---- epilogue: lane holds rows fg*4+r, col fm of each 16x16 frag ----
#pragma unroll
  for (int mt = 0; mt < FM; ++mt) {
#pragma unroll
    for (int nt = 0; nt < FN; ++nt) {
      const int col  = bn + wn + nt * 16 + fm;
      const int row0 = bm + wm + mt * 16 + fg * 4;
      if (EPI == 0) {
        if (col < 768) {                      // q or k region
          us* qk = (us*)O0;
#pragma unroll
          for (int r = 0; r < 4; ++r)
            qk[(size_t)(row0 + r) * 768 + col] = f2bf(acc[mt][nt][r]);
        } else {                              // v -> transposed [B*H][64][256]
          const int d = col - 768;
          const int hh = d >> 6, dd = d & 63;
          const int bI = row0 >> 8, t0 = row0 & 255;
          us* vt = (us*)O1;
          ushort4 pk;
          pk.x = f2bf(acc[mt][nt][0]); pk.y = f2bf(acc[mt][nt][1]);
          pk.z = f2bf(acc[mt][nt][2]); pk.w = f2bf(acc[mt][nt][3]);
          *reinterpret_cast<ushort4*>(vt + ((size_t)((bI * H_ + hh) * 64 + dd)) * 256 + t0) = pk;
        }
      } else if (EPI == 1) {
        us* o = (us*)O0;
        const float bc = bias[col];
#pragma unroll
        for (int r = 0; r < 4; ++r) {
          const size_t idx = (size_t)(row0 + r) * N + col;
          o[idx] = f2bf(acc[mt][nt][r] + bc + bf2f(Res[idx]));
        }
      } else if (EPI == 2) {
        us* o = (us*)O0;
        const float bc = bias[col];
#pragma unroll
        for (int r = 0; r < 4; ++r)
          o[(size_t)(row0 + r) * N + col] = f2bf(fmaxf(acc[mt][nt][r] + bc, 0.f));
      } else {
        if (col < V_) {
          float* o = (float*)O0;
          const float bc = bias[col];
#pragma unroll
          for (int r = 0; r < 4; ++r)
            o[(size_t)(row0 + r) * V_ + col] = acc[mt][nt][r] + bc;
        }
      }
    }
  }
}

// ---------------------------------------------------------------------------
// MFMA flash attention. Block = (b, h, 64-query tile); 4 waves x 16 queries.
// K/V tiles staged in LDS (double-buffered, issue-early 2-phase), CHPR=8
// XOR swizzle. qk: [BT][768] bf16; vT: [B*H][64][256] bf16; ab: [BT][384].
// ---------------------------------------------------------------------------
__global__ __launch_bounds__(256)
void attn_mfma(const us* __restrict__ qk, const us* __restrict__ vT,
               us* __restrict__ ab) {
  __shared__ us Ks[2][64 * 64];
  __shared__ us Vs[2][64 * 64];
  __shared__ us Plds[4][16 * 72];   // per-wave P tile, stride 72 (pad)
  const int tid = threadIdx.x, w = tid >> 6, l = tid & 63;
  const int m = l & 15, g = l >> 4;
  const int bi = xcd_swz(blockIdx.x, gridDim.x);
  const int b = bi / 24, rem = bi - b * 24, h = rem >> 2, qt = rem & 3;
  const int qrow = (b << 8) + (qt << 6) + (w << 4);
  const us* Kg = qk + (size_t)(b << 8) * 768 + 384 + h * 64;  // + kt*64 rows
  const us* Vg = vT + (size_t)(b * H_ + h) * 64 * 256;        // + kt*64 cols

  short8 qf0, qf1;
  {
    const us* qp = qk + (size_t)(qrow + m) * 768 + h * 64 + g * 8;
    qf0 = *(const short8*)qp;
    qf1 = *(const short8*)(qp + 32);
  }
  float mrow[4], ssum[4];
  f32x4 o[4];
  const f32x4 zz = {0.f, 0.f, 0.f, 0.f};
#pragma unroll
  for (int r = 0; r < 4; ++r) { mrow[r] = -1e30f; ssum[r] = 0.f; o[r] = zz; }

  stageG<64, 8, 256>(Kg, 768, Ks[0], tid);
  stageG<64, 8, 256>(Vg, 256, Vs[0], tid);
  __syncthreads();

  int cur = 0;
  for (int kt = 0; kt <= qt; ++kt) {
    if (kt < qt) {
      stageG<64, 8, 256>(Kg + (size_t)(kt + 1) * 64 * 768, 768, Ks[cur ^ 1], tid);
      stageG<64, 8, 256>(Vg + (kt + 1) * 64,               256, Vs[cur ^ 1], tid);
    }
    // ---- S = Q K^T (16 queries x 64 keys) from LDS ----
    f32x4 s[4];
#pragma unroll
    for (int nt = 0; nt < 4; ++nt) {
      const int row = nt * 16 + m;
      const int sw  = row & 7;
      short8 kf0 = *(const short8*)(Ks[cur] + row * 64 + ((g ^ sw) << 3));
      short8 kf1 = *(const short8*)(Ks[cur] + row * 64 + (((4 | g) ^ sw) << 3));
      f32x4 z = zz;
      z = __builtin_amdgcn_mfma_f32_16x16x32_bf16(qf0, kf0, z, 0, 0, 0);
      z = __builtin_amdgcn_mfma_f32_16x16x32_bf16(qf1, kf1, z, 0, 0, 0);
      s[nt] = z;
    }
    // ---- mask + online softmax ----
    const bool diag = (kt == qt);
    float p[4][4], tmax[4];
#pragma unroll
    for (int r = 0; r < 4; ++r) tmax[r] = -1e30f;
#pragma unroll
    for (int nt = 0; nt < 4; ++nt)
#pragma unroll
      for (int r = 0; r < 4; ++r) {
        float v = s[nt][r] * 0.125f;
        if (diag) {
          const int key = nt * 16 + m;
          const int qq  = (w << 4) + (g << 2) + r;
          if (key > qq) v = -1e30f;
        }
        p[nt][r] = v;
        tmax[r] = fmaxf(tmax[r], v);
      }
#pragma unroll
    for (int xm = 1; xm < 16; xm <<= 1)
#pragma unroll
      for (int r = 0; r < 4; ++r) tmax[r] = fmaxf(tmax[r], __shfl_xor(tmax[r], xm));
    float sc[4], tsum[4];
#pragma unroll
    for (int r = 0; r < 4; ++r) {
      const float nm = fmaxf(mrow[r], tmax[r]);
      sc[r] = __expf(mrow[r] - nm);
      mrow[r] = nm;
      tsum[r] = 0.f;
    }
#pragma unroll
    for (int nt = 0; nt < 4; ++nt)
#pragma unroll
      for (int r = 0; r < 4; ++r) {
        p[nt][r] = __expf(p[nt][r] - mrow[r]);
        tsum[r] += p[nt][r];
      }
#pragma unroll
    for (int xm = 1; xm < 16; xm <<= 1)
#pragma unroll
      for (int r = 0; r < 4; ++r) tsum[r] += __shfl_xor(tsum[r], xm);
#pragma unroll
    for (int r = 0; r < 4; ++r) ssum[r] = ssum[r] * sc[r] + tsum[r];
#pragma unroll
    for (int nt = 0; nt < 4; ++nt)
#pragma unroll
      for (int r = 0; r < 4; ++r) o[nt][r] *= sc[r];
    // ---- P -> LDS (bf16, C-layout -> A-layout transpose via LDS) ----
#pragma unroll
    for (int nt = 0; nt < 4; ++nt)
#pragma unroll
      for (int r = 0; r < 4; ++r)
        Plds[w][(g * 4 + r) * 72 + nt * 16 + m] = f2bf(p[nt][r]);
    // ---- O += P V (V from LDS) ----
#pragma unroll
    for (int kc = 0; kc < 2; ++kc) {
      short8 pa = *(const short8*)&Plds[w][m * 72 + kc * 32 + g * 8];
#pragma unroll
      for (int nd = 0; nd < 4; ++nd) {
        const int row = nd * 16 + m;
        short8 vf = *(const short8*)(Vs[cur] + row * 64 + ((((kc << 2) | g) ^ (row & 7)) << 3));
        o[nd] = __builtin_amdgcn_mfma_f32_16x16x32_bf16(pa, vf, o[nd], 0, 0, 0);
      }
    }
    __syncthreads();   // staged next tile arrived; all reads of cur done
    cur ^= 1;
  }
  // ---- normalize + write ----
#pragma unroll
  for (int r = 0; r < 4; ++r) {
    const float inv = 1.f / ssum[r];
    const size_t rowoff = (size_t)(qrow + g * 4 + r) * 384 + h * 64;
#pragma unroll
    for (int nd = 0; nd < 4; ++nd)
      ab[rowoff + nd * 16 + m] = f2bf(o[nd][r] * inv);
  }
}

// ---------------------------------------------------------------------------
extern "C" void kernel_launch(void* const* d_in, const int* in_sizes, int n_in,
                              void* d_out, int out_size, void* d_ws, size_t ws_size,
                              hipStream_t stream) {
  const int*   x    = (const int*)  d_in[0];
  const float* tok  = (const float*)d_in[1];
  const float* pos  = (const float*)d_in[2];
  const float* Wq   = (const float*)d_in[3];
  const float* Wk   = (const float*)d_in[4];
  const float* Wv   = (const float*)d_in[5];
  const float* Wpr  = (const float*)d_in[6];
  const float* bpr  = (const float*)d_in[7];
  const float* W1   = (const float*)d_in[8];
  const float* b1   = (const float*)d_in[9];
  const float* W2   = (const float*)d_in[10];
  const float* b2   = (const float*)d_in[11];
  const float* ln1g = (const float*)d_in[12];
  const float* ln1b = (const float*)d_in[13];
  const float* ln2g = (const float*)d_in[14];
  const float* ln2b = (const float*)d_in[15];
  const float* lnfg = (const float*)d_in[16];
  const float* lnfb = (const float*)d_in[17];
  const float* Wlm  = (const float*)d_in[18];
  const float* blm  = (const float*)d_in[19];
  float* out = (float*)d_out;

  char* W = (char*)d_ws;
  us* h    = (us*)(W + 0);                  // [BT][384] bf16   12.58 MB
  us* hn   = (us*)(W + 12582912);           // [BT][384] bf16   12.58 MB
  us* qkb  = (us*)(W + 25165824);           // [BT][768] bf16   25.17 MB
  us* vTb  = (us*)(W + 50331648);           // [B*H][64][256]   12.58 MB
  us* abb  = (us*)(W + 62914560);           // [BT][384] bf16   12.58 MB
  us* ffa  = (us*)(W + 25165824);           // [BT][1536] bf16 (aliases qk+vT+ab)
  us* qkvT = (us*)(W + 75497472);           // [L][1152][384] bf16
  us* projT= (us*)(W + 80805888);           // [L][384][384]
  us* W1T  = (us*)(W + 82575360);           // [L][1536][384]
  us* W2T  = (us*)(W + 89653248);           // [L][384][1536]
  us* WlmT = (us*)(W + 96731136);           // [128][384] (rows 65+ zero)

  // ---- weight conversion ----
  transpose_w<<<dim3(12,12,6), 256, 0, stream>>>(Wq,  qkvT,           384, 384, 384, 147456, 442368);
  transpose_w<<<dim3(12,12,6), 256, 0, stream>>>(Wk,  qkvT + 147456,  384, 384, 384, 147456, 442368);
  transpose_w<<<dim3(12,12,6), 256, 0, stream>>>(Wv,  qkvT + 294912,  384, 384, 384, 147456, 442368);
  transpose_w<<<dim3(12,12,6), 256, 0, stream>>>(Wpr, projT,          384, 384, 384, 147456, 147456);
  transpose_w<<<dim3(48,12,6), 256, 0, stream>>>(W1,  W1T,            384, 1536, 1536, 589824, 589824);
  transpose_w<<<dim3(12,48,6), 256, 0, stream>>>(W2,  W2T,            1536, 384, 384, 589824, 589824);
  transpose_w<<<dim3(4,12,1),  256, 0, stream>>>(Wlm, WlmT,           384, 65, 128, 0, 0);

  embed_kernel<<<3072, 256, 0, stream>>>(x, tok, pos, h);

  for (int l = 0; l < L_; ++l) {
    ln_kernel<1><<<BT_/4, 256, 0, stream>>>(h, hn, ln1g + l*E_, ln1b + l*E_);
    // QKV: 256x128 tiles -> 9 * 64 = 576 blocks, 512 threads
    gemm_mfma<4,2,4,4,0><<<576, 512, 0, stream>>>(
        hn, qkvT + (size_t)l*442368, nullptr, nullptr, qkb, vTb, 1152, 384, 9);
    attn_mfma<<<B_*H_*4, 256, 0, stream>>>(qkb, vTb, abb);
    // proj: 128x128 tiles -> 3 * 128 = 384 blocks
    gemm_mfma<2,2,4,4,1><<<384, 256, 0, stream>>>(
        abb, projT + (size_t)l*147456, bpr + l*E_, h, h, nullptr, 384, 384, 3);
    ln_kernel<1><<<BT_/4, 256, 0, stream>>>(h, hn, ln2g + l*E_, ln2b + l*E_);
    // FF1: 256x128 tiles -> 12 * 64 = 768 blocks
    gemm_mfma<4,2,4,4,2><<<768, 512, 0, stream>>>(
        hn, W1T + (size_t)l*589824, b1 + l*FF_, nullptr, ffa, nullptr, 1536, 384, 12);
    // FF2: 256x128 tiles, K=1536 -> 3 * 64 = 192 blocks
    gemm_mfma<4,2,4,4,1><<<192, 512, 0, stream>>>(
        ffa, W2T + (size_t)l*589824, b2 + l*E_, h, h, nullptr, 384, 1536, 3);
  }

  ln_kernel<0><<<BT_/4, 256, 0, stream>>>(h, hn, lnfg, lnfb);
  // LM head: 128x128 tiles -> 1 * 128 = 128 blocks
  gemm_mfma<2,2,4,4,3><<<128, 256, 0, stream>>>(
      hn, WlmT, blm, nullptr, out, nullptr, 128, 384, 1);
}